// Round 2
// baseline (392.792 us; speedup 1.0000x reference)
//
#include <hip/hip_runtime.h>

typedef unsigned short u16;
typedef __attribute__((ext_vector_type(8))) short bf16x8;
typedef __attribute__((ext_vector_type(4))) float f32x4;

// Problem constants
#define LSEQ 512
#define BN   64
#define DD   128
#define HH   128
#define CHUNK 64    // embed rows staged in LDS per refill (16 KiB bf16)

// fp32 inputs (verified R7 diagnostic); one fp32 scalar output (R8-R11 PASS).

__device__ __forceinline__ u16 f2b(float f) {
  union { float f; unsigned i; } v; v.f = f;
  unsigned i = v.i;
  return (u16)((i + 0x7fffu + ((i >> 16) & 1u)) >> 16);
}
__device__ __forceinline__ float rcpf(float x) {
  return __builtin_amdgcn_rcpf(x);
}
__device__ __forceinline__ float sigm(float x) {
  return rcpf(1.f + __expf(-x));               // v_exp + v_rcp, no div chain
}
__device__ __forceinline__ float tanh_f(float x) {
  x = fminf(15.f, fmaxf(-15.f, x));
  float e = __expf(2.f * x);
  return (e - 1.f) * rcpf(e + 1.f);
}
__device__ __forceinline__ float clampg(float x, float hi) {
  return fmaxf(-hi, fminf(hi, x));  // transparent: true |gates|<0.5
}

// ---------------------------------------------------------------------------
// Two 512-step recurrences, fused. blockIdx 0..63: fwd LSTM sample b;
// 64..127: tree-LSTM chain (left-deep). Block = 512 threads (8 waves).
// Tile g of wave w covers gate columns n = g*128 + w*16 + lr; C-rows of the
// h-matvec MFMA are broadcast-identical, so EVERY lane holds all 4 gates of
// d = w*16 + (l&15).
//
// Round-14 (this round): LDS-pipe decongestion of the serial step.
//  * R13's 4 ds_bpermute/step/wave (e-broadcast) -> ONE ds_read_b128/step:
//    after each 16-step EBATCH, the wave writes its EB regs to a wave-private
//    estage[w][step][lr][gate] region (4 ds_write_b128, amortized 0.25/step);
//    each step reads {e0..e3} for its dim in a single b128. DS instrs per CU
//    per step drop 72 -> ~50 (LDS pipe was the top per-step consumer:
//    32 aK-reads + 32 bpermutes + 8 writes at ~6-12 cyc each).
//  * 16-step groups fully unrolled with compile-time step index S: aK buffer
//    parity (S&1), estage offset S*256 and the tail checks all fold into
//    immediates -> zero per-step address math / branches in steady state.
//  * CHUNK 128 -> 64 so estage (32 KiB) + echunk (16 KiB) fit static LDS.
//    Same total global traffic, just 2x refill cadence.
//  * Bit-exact vs R13: e-values round-trip LDS as unchanged fp32 bits; gate
//    sum order (acch + e) + bias, MFMA sequences, nonlinearity unchanged.
//  * Zero global memory ops inside the step loop (echunk staging, R11).
// ---------------------------------------------------------------------------
__global__ __launch_bounds__(512, 1) void chains_kernel(
    const int* __restrict__ x, const int* __restrict__ lengths,
    const float* __restrict__ embed,
    const float* __restrict__ Wih_f, const float* __restrict__ Whh_f,
    const float* __restrict__ b_f,
    const float* __restrict__ Wiou, const float* __restrict__ Uiou,
    const float* __restrict__ biou,
    const float* __restrict__ Wf, const float* __restrict__ Uf,
    const float* __restrict__ bfv,
    float* __restrict__ sent_vec, float* __restrict__ t_state,
    float* __restrict__ t_hidden) {
  const bool tree = blockIdx.x >= BN;
  const int b = blockIdx.x & (BN - 1);
  int len = lengths[b];
  len = (len < 1) ? 1 : (len > LSEQ ? LSEQ : len);
  const int tid = threadIdx.x;
  const int w = tid >> 6, l = tid & 63, lr = l & 15, lq = l >> 4;
  const int d = w * 16 + lr;  // hidden index this lane's gates belong to

  __shared__ __align__(16) u16 echunk[CHUNK * 128];  // staged e rows, bf16 (XOR-swizzled)
  __shared__ __align__(16) float estage[8 * 16 * 16 * 4];  // [w][s][lr][g] fp32
  __shared__ __align__(16) u16 aK[2][128];           // h bf16, double-buffered
  __shared__ int toks[LSEQ];                         // token ids (clamped)

  // ---- Resident B fragments, split into h-half (k<128) and e-half (k>=128).
  // MFMA #ks consumes B[k = ks*32 + lq*8 + j][n], j = 0..7.
  bf16x8 bfragH[4][4], bfragE[4][4];
  if (!tree) {
#pragma unroll
    for (int g = 0; g < 4; g++) {
      const int n = g * 128 + w * 16 + lr;
#pragma unroll
      for (int ks = 0; ks < 4; ks++) {
        const int k0 = ks * 32 + lq * 8;
        {
          float4 lo = *(const float4*)(Whh_f + n * 128 + k0);
          float4 hi = *(const float4*)(Whh_f + n * 128 + k0 + 4);
          bf16x8 fr;
          fr[0] = (short)f2b(lo.x); fr[1] = (short)f2b(lo.y);
          fr[2] = (short)f2b(lo.z); fr[3] = (short)f2b(lo.w);
          fr[4] = (short)f2b(hi.x); fr[5] = (short)f2b(hi.y);
          fr[6] = (short)f2b(hi.z); fr[7] = (short)f2b(hi.w);
          bfragH[g][ks] = fr;
        }
        {
          float4 lo = *(const float4*)(Wih_f + n * 128 + k0);
          float4 hi = *(const float4*)(Wih_f + n * 128 + k0 + 4);
          bf16x8 fr;
          fr[0] = (short)f2b(lo.x); fr[1] = (short)f2b(lo.y);
          fr[2] = (short)f2b(lo.z); fr[3] = (short)f2b(lo.w);
          fr[4] = (short)f2b(hi.x); fr[5] = (short)f2b(hi.y);
          fr[6] = (short)f2b(hi.z); fr[7] = (short)f2b(hi.w);
          bfragE[g][ks] = fr;
        }
      }
    }
  } else {
#pragma unroll
    for (int g = 0; g < 4; g++) {
      const int col = (g < 3) ? (g * 128 + w * 16 + lr) : (w * 16 + lr);
#pragma unroll
      for (int ks = 0; ks < 4; ks++) {
        const int k0 = ks * 32 + lq * 8;
        bf16x8 fh, fe;
#pragma unroll
        for (int j = 0; j < 8; j++) {
          const int k = k0 + j;
          float vh, ve;
          if (g < 3) { vh = Uiou[k * 384 + col]; ve = Wiou[k * 384 + col]; }
          else       { vh = Uf[k * 128 + col];   ve = Wf[k * 128 + col]; }
          fh[j] = (short)f2b(vh);
          fe[j] = (short)f2b(ve);
        }
        bfragH[g][ks] = fh;
        bfragE[g][ks] = fe;
      }
    }
  }

  // Per-lane biases for the 4 gates of d (all lanes; quadrants identical).
  float bias0, bias1, bias2, bias3;
  if (!tree) {
    bias0 = b_f[d];        bias1 = b_f[128 + d];
    bias2 = b_f[256 + d];  bias3 = b_f[384 + d];
  } else {
    bias0 = biou[d];       bias1 = biou[128 + d];
    bias2 = biou[256 + d]; bias3 = bfv[d];
  }

  // Token ids -> LDS (clamped); h(0) = 0 in both buffers.
  for (int i = tid; i < LSEQ; i += 512) {
    int tt = (i < len) ? i : (len - 1);
    toks[i] = x[tt * BN + b];
  }
  if (tid < HH) { aK[0][tid] = 0; aK[1][tid] = 0; }

  // Per-lane LDS byte bases (loop-invariant; per-step offsets are immediates).
  char* const es_base = (char*)estage;
  const int erd = (w << 12) + (lr << 4);               // estage read:  + S*256
  const int ewr = (w << 12) + (lq << 10) + (lr << 4);  // estage write: + rg*256
  const char* const ak_rd = (const char*)aK + (lq << 4);  // + (S&1)*256 + ks*64
  u16* const ak_wr = &aK[0][0] + d;                       // + ((S&1)^1)*128

  const f32x4 zf = (f32x4){0.f, 0.f, 0.f, 0.f};
  float c = 0.f, h = 0.f;
  int t = 0;

// ---- Batched e-half for steps [T0, T0+16): A row r = e(T0+r), r = lane&15.
// Output staged to wave-private estage: lane q*16+lr holds step q*4+rg at
// reg rg (m89 C/D layout); write {EB0..EB3}[rg] as one b128 per rg.
#define EBATCH(T0)                                                            \
  {                                                                           \
    const int rb = ((T0) & (CHUNK - 1)) + lr;                                 \
    bf16x8 ae[4];                                                             \
    _Pragma("unroll")                                                         \
    for (int ks = 0; ks < 4; ks++) {                                          \
      int bo = (rb * 256 + ks * 64 + lq * 16) ^ ((rb & 7) << 4);              \
      ae[ks] = *(const bf16x8*)((const char*)echunk + bo);                    \
    }                                                                         \
    f32x4 EBv[4];                                                             \
    _Pragma("unroll")                                                         \
    for (int g = 0; g < 4; g++)                                               \
      EBv[g] = __builtin_amdgcn_mfma_f32_16x16x32_bf16(ae[0], bfragE[g][0],   \
                                                       zf, 0, 0, 0);          \
    _Pragma("unroll")                                                         \
    for (int ks = 1; ks < 4; ks++)                                            \
      _Pragma("unroll")                                                       \
      for (int g = 0; g < 4; g++)                                             \
        EBv[g] = __builtin_amdgcn_mfma_f32_16x16x32_bf16(                     \
            ae[ks], bfragE[g][ks], EBv[g], 0, 0, 0);                          \
    _Pragma("unroll")                                                         \
    for (int rg = 0; rg < 4; rg++) {                                          \
      f32x4 wv = {EBv[0][rg], EBv[1][rg], EBv[2][rg], EBv[3][rg]};            \
      *(f32x4*)(es_base + ewr + rg * 256) = wv;                               \
    }                                                                         \
  }

// ---- One step, compile-time step index S in [0,16). aK parity, estage
// offset and tail predicate all fold to immediates.
#define STEPB(S)                                                              \
  {                                                                           \
    bf16x8 ah[4];                                                             \
    _Pragma("unroll")                                                         \
    for (int ks = 0; ks < 4; ks++)                                            \
      ah[ks] = *(const bf16x8*)(ak_rd + ((S) & 1) * 256 + ks * 64);           \
    f32x4 ev = *(const f32x4*)(es_base + erd + (S) * 256);                    \
    f32x4 acch[4];                                                            \
    _Pragma("unroll")                                                         \
    for (int g = 0; g < 4; g++)                                               \
      acch[g] = __builtin_amdgcn_mfma_f32_16x16x32_bf16(ah[0], bfragH[g][0],  \
                                                        zf, 0, 0, 0);         \
    _Pragma("unroll")                                                         \
    for (int ks = 1; ks < 4; ks++)                                            \
      _Pragma("unroll")                                                       \
      for (int g = 0; g < 4; g++)                                             \
        acch[g] = __builtin_amdgcn_mfma_f32_16x16x32_bf16(                    \
            ah[ks], bfragH[g][ks], acch[g], 0, 0, 0);                         \
    float g0 = clampg(acch[0][0] + ev[0] + bias0, 16.f);                      \
    float g1 = clampg(acch[1][0] + ev[1] + bias1, 16.f);                      \
    float g2 = clampg(acch[2][0] + ev[2] + bias2, 16.f);                      \
    float g3 = clampg(acch[3][0] + ev[3] + bias3, 16.f);                      \
    if (!tree) {                                                              \
      float ii = sigm(g0), ff = sigm(g1), gg = tanh_f(g2), oo = sigm(g3);     \
      c = ff * c + ii * gg;                                                   \
      h = oo * tanh_f(c);                                                     \
    } else {                                                                  \
      float ii = sigm(g0), oo = sigm(g1), uu = tanh_f(g2), fl = sigm(g3);     \
      c = ii * uu + fl * c;                                                   \
      h = oo * tanh_f(c);                                                     \
    }                                                                         \
    if (l < 16) ak_wr[(((S) & 1) ^ 1) * 128] = f2b(h);                        \
    __syncthreads();                                                          \
  }

// Tail step: block-uniform predicate (tend identical across waves), so the
// embedded __syncthreads is uniformly executed or skipped.
#define STEPT(S) if (tb + (S) < tend) STEPB(S)

  for (int c0 = 0; c0 < len; c0 += CHUNK) {
    __syncthreads();  // prev chunk fully consumed (and toks/h0 visible)

    // ---- Refill: stage rows [c0, c0+CHUNK) as bf16 into echunk (swizzled).
#pragma unroll
    for (int j = 0; j < 4; j++) {
      int u = tid + j * 512;
      int r = u >> 5;
      int c4 = (u & 31) * 4;
      int row = toks[c0 + r];
      float4 v = *(const float4*)(embed + (size_t)row * DD + c4);
      u16 eb[4] = {f2b(v.x), f2b(v.y), f2b(v.z), f2b(v.w)};
      int bo = (r * 256 + c4 * 2) ^ ((r & 7) << 4);
      *(unsigned long long*)((char*)echunk + bo) =
          *(const unsigned long long*)eb;
    }
    __syncthreads();  // chunk visible

    const int tend = (c0 + CHUNK < len) ? c0 + CHUNK : len;
    // Full 16-step groups: no per-step checks, all offsets immediate.
    while (t + 16 <= tend) {
      EBATCH(t)
      STEPB(0)  STEPB(1)  STEPB(2)  STEPB(3)
      STEPB(4)  STEPB(5)  STEPB(6)  STEPB(7)
      STEPB(8)  STEPB(9)  STEPB(10) STEPB(11)
      STEPB(12) STEPB(13) STEPB(14) STEPB(15)
      t += 16;
    }
    // Tail group (only at the very end of the sequence).
    if (t < tend) {
      const int tb = t;
      EBATCH(tb)
      STEPT(0)  STEPT(1)  STEPT(2)  STEPT(3)
      STEPT(4)  STEPT(5)  STEPT(6)  STEPT(7)
      STEPT(8)  STEPT(9)  STEPT(10) STEPT(11)
      STEPT(12) STEPT(13) STEPT(14)
      t = tend;
    }
  }
#undef STEPT
#undef STEPB
#undef EBATCH

  if (l < 16) {
    if (!tree) {
      sent_vec[b * HH + d] = h;
    } else {
      t_state[b * HH + d] = c;
      t_hidden[b * HH + d] = h;
    }
  }
}

// ---------------------------------------------------------------------------
// Head: tree_out = [t_state | w1*t_hidden + w2*sent_vec]; sigmoid logits ->
// clipped BCE vs one-hot(y); loss = -mean over (B, NC=2) = 128 terms. fp32.
// ---------------------------------------------------------------------------
__global__ __launch_bounds__(128) void final_kernel(
    const int* __restrict__ y, const float* __restrict__ sent_vec,
    const float* __restrict__ t_state, const float* __restrict__ t_hidden,
    const float* __restrict__ Wout, const float* __restrict__ bout,
    const float* __restrict__ w1, const float* __restrict__ w2,
    float* __restrict__ out) {
  int tid = threadIdx.x;  // (b, cls)
  int b = tid >> 1, cls = tid & 1;
  float W1 = w1[0], W2 = w2[0];
  const float* wrow = Wout + cls * 256;
  float acc = bout[cls];
  for (int j = 0; j < HH; j++)
    acc += t_state[b * HH + j] * wrow[j];
  for (int j = 0; j < HH; j++)
    acc += (W1 * t_hidden[b * HH + j] + W2 * sent_vec[b * HH + j]) * wrow[128 + j];
  float p = 1.f / (1.f + __expf(-acc));
  p = fminf(1.f - 1e-7f, fmaxf(1e-7f, p));
  int yy = y[b]; yy = yy < 0 ? 0 : (yy > 1 ? 1 : yy);
  float term = (cls == yy) ? __logf(p) : __logf(1.f - p);
  __shared__ float red[128];
  red[tid] = term;
  __syncthreads();
  for (int s = 64; s > 0; s >>= 1) {
    if (tid < s) red[tid] += red[tid + s];
    __syncthreads();
  }
  if (tid == 0) out[0] = -red[0] / 128.f;
}

// ---------------------------------------------------------------------------
extern "C" void kernel_launch(void* const* d_in, const int* in_sizes, int n_in,
                              void* d_out, int out_size, void* d_ws, size_t ws_size,
                              hipStream_t stream) {
  (void)in_sizes; (void)n_in; (void)out_size; (void)ws_size;
  const int*   x       = (const int*)d_in[0];
  const int*   y       = (const int*)d_in[1];
  // d_in[2] = p (unused by reference)
  const int*   lengths = (const int*)d_in[3];
  // d_in[4], d_in[5] = left/right child: fixed left-deep chain (j-1 / -1)
  const float* embed   = (const float*)d_in[6];
  const float* Wih_f   = (const float*)d_in[7];
  const float* Whh_f   = (const float*)d_in[8];
  const float* b_f     = (const float*)d_in[9];
  // d_in[10..12] = backward-LSTM weights (result unused by reference)
  const float* Wiou    = (const float*)d_in[13];
  const float* Uiou    = (const float*)d_in[14];
  const float* biou    = (const float*)d_in[15];
  const float* Wf      = (const float*)d_in[16];
  const float* Uf      = (const float*)d_in[17];
  const float* bfv     = (const float*)d_in[18];
  const float* Wout    = (const float*)d_in[19];
  const float* bout    = (const float*)d_in[20];
  const float* w1      = (const float*)d_in[21];
  const float* w2      = (const float*)d_in[22];

  // Workspace: 3 fp32 [64][128] vectors = 96 KiB.
  float* sent_vec = (float*)d_ws;
  float* t_state  = sent_vec + BN * HH;
  float* t_hidden = t_state + BN * HH;

  chains_kernel<<<128, 512, 0, stream>>>(x, lengths, embed,
                                         Wih_f, Whh_f, b_f,
                                         Wiou, Uiou, biou, Wf, Uf, bfv,
                                         sent_vec, t_state, t_hidden);
  final_kernel<<<1, 128, 0, stream>>>(y, sent_vec, t_state, t_hidden,
                                      Wout, bout, w1, w2, (float*)d_out);
}